// Round 23
// baseline (184.493 us; speedup 1.0000x reference)
//
#include <hip/hip_runtime.h>

typedef _Float16 f16x8 __attribute__((ext_vector_type(8)));
typedef _Float16 f16x4 __attribute__((ext_vector_type(4)));
typedef __fp16 fp16v2 __attribute__((ext_vector_type(2)));
typedef _Float16 f16v2 __attribute__((ext_vector_type(2)));
typedef short short8 __attribute__((ext_vector_type(8)));
typedef float f32x16 __attribute__((ext_vector_type(16)));

#define DD 512
#define NG 512

#define MEMFENCE asm volatile("" ::: "memory")

static __device__ __forceinline__ f16v2 pk16(float a, float b) {
  fp16v2 p = __builtin_amdgcn_cvt_pkrtz(a, b);
  return __builtin_bit_cast(f16v2, p);
}

// fast tanh via exp2: tanh(v) = 1 - 2/(exp2(v*2*log2e)+1)  (~1e-6 abs err)
static __device__ __forceinline__ float fast_tanh(float v) {
  float e = __builtin_amdgcn_exp2f(v * 2.8853900817779268f);
  return 1.0f - 2.0f * __builtin_amdgcn_rcpf(e + 1.0f);
}

// Whl layout (f16 RTE): [ny(2)][kt(32)][ct(8)][lane(64)=khalf*32+c31][8 f16]
// B-fragment = 1 KB contiguous at kt*8192 + ct*1024 + lane*16 -> a direct
// global_load_dwordx4 per fragment is perfectly coalesced.  Whl = 512 KB,
// read by all blocks -> L2-resident.
__global__ __launch_bounds__(256) void k_convert_w(const float* __restrict__ W,
                                                   unsigned char* __restrict__ Whl) {
  int t = blockIdx.x * 256 + threadIdx.x;   // 32768 = 512 W-rows x 64 kgroups(8)
  int r512 = t >> 6, kg = t & 63;
  int ny = r512 >> 8, col = r512 & 255;
  int ct = col >> 5, c31 = col & 31;
  int kt = kg >> 1, khalf = kg & 1;
  const float* p = W + (size_t)r512 * DD + kg * 8;
  short8 h;
#pragma unroll
  for (int j = 0; j < 8; ++j) {
    _Float16 hh = (_Float16)p[j];              // RTE
    h[j] = (short)__builtin_bit_cast(unsigned short, hh);
  }
  unsigned char* dst = Whl + (size_t)ny * 262144 + (size_t)kt * 8192 +
                       ct * 1024 + (khalf * 32 + c31) * 16;
  *(short8*)dst = h;
}

// Fused GEMM(tanh-gate)+query-dot.  R22 schedule (best measured) + xf16
// side-channel: ny==0 blocks also store the already-converted f16 x tile to
// workspace (4x 8B stores per thread per body; L2 write-back merges halves
// into full lines) so the softmax kernel re-reads x at HALF the bytes.
// B: straight from L2-resident Whl to VGPRs (b0/b1 single-kt sets).
// A: f16 in LDS, conflict-free [kh-plane][row][16B], ring-2.
// Wave = 64 rows x 128 cols (acc[2][4] = 128 AGPR); block = 4 waves = 128
// rows x 256 cols (ny = col half); 2-kt bodies, fully unrolled; per body
// 1 barrier + 1 lgkm0; all global waits compiler-counted.  17.4 KB LDS.
__global__ __launch_bounds__(256, 2) void k_gemm_score(
    const float* __restrict__ x, const unsigned char* __restrict__ Whl,
    const float* __restrict__ bias, const float* __restrict__ query,
    float* __restrict__ score_part, _Float16* __restrict__ xf16,
    int writeX, int N) {
  __shared__ unsigned char ldsA[2][8192];
  __shared__ float comb[2][128];
  const int tid = threadIdx.x;
  const int wave = tid >> 6;
  const int lane = tid & 63;
  const int l31 = lane & 31;
  const int kh = lane >> 5;          // k-half within fragment
  const int rg = wave >> 1;          // row-group: rows rg*64..rg*64+63
  const int cg = wave & 1;           // col-group: cts cg*4..cg*4+3
  const int ny = blockIdx.x;
  const int brow0 = blockIdx.y * 128;
  const bool dow = writeX && (ny == 0);

  // B direct-load base: fragment (kt, ct=cg*4+t) at + kt*8192 + t*1024
  const unsigned char* bsrc = Whl + (size_t)ny * 262144 + cg * 4096 +
                              (size_t)lane * 16;

  // A: thread covers chunks (row = tid>>2 and +64, kq = tid&3) of each
  // 128-row x 16-k slice.
  const float* asrc = x + (size_t)(brow0 + (tid >> 2)) * DD + (tid & 3) * 4;
  // f16 write: [kt-in-pair(4KB)][kh(2KB)][row(128)x16B], half = kq&1:
  const int awoff = ((tid & 3) >> 1) * 2048 + (tid >> 2) * 16 + (tid & 1) * 8;
  // f16 read: fragment row rg*64 + f*32 + l31, plane kh
  const int aroff = kh * 2048 + (rg * 64 + l31) * 16;
  // xf16 store base (elements): row (brow0 + tid>>2), k-offset (tid&3)*4
  _Float16* xwb = xf16 + (size_t)(brow0 + (tid >> 2)) * DD + (tid & 3) * 4;

  f32x16 acc[2][4];
#pragma unroll
  for (int f = 0; f < 2; ++f)
#pragma unroll
    for (int j = 0; j < 4; ++j)
#pragma unroll
      for (int r = 0; r < 16; ++r) acc[f][j][r] = 0.f;

  float4 aB[4];        // A reg staging [kt-in-pair][chunk c]
  f16x8 b0[4], b1[4];  // B fragment sets (single kt each)

#define AISSUE(S)                                                           \
  do {                                                                      \
    _Pragma("unroll")                                                       \
    for (int j = 0; j < 2; ++j)                                             \
      _Pragma("unroll")                                                     \
      for (int c = 0; c < 2; ++c)                                           \
        aB[j * 2 + c] = *(const float4*)(asrc + (size_t)c * 64 * DD +       \
                                         ((2 * (S) + j) & 31) * 16);        \
  } while (0)

#define AWRITE(S)                                                           \
  do {                                                                      \
    unsigned char* base_ = &ldsA[(S) & 1][0];                               \
    _Pragma("unroll")                                                       \
    for (int j = 0; j < 2; ++j)                                             \
      _Pragma("unroll")                                                     \
      for (int c = 0; c < 2; ++c) {                                         \
        const float4 v_ = aB[j * 2 + c];                                    \
        f16v2 lo_ = pk16(v_.x, v_.y);                                       \
        f16v2 hi_ = pk16(v_.z, v_.w);                                       \
        f16x4 w_ = {lo_[0], lo_[1], hi_[0], hi_[1]};                        \
        *(f16x4*)(base_ + j * 4096 + awoff + c * 1024) = w_;                \
        if (dow)                                                            \
          *(f16x4*)(xwb + (size_t)c * 64 * DD + ((2 * (S) + j) & 31) * 16) = w_; \
      }                                                                     \
  } while (0)

#define BLOAD(KT, R)                                                        \
  do {                                                                      \
    const unsigned char* sb_ = bsrc + (size_t)((KT) & 31) * 8192;           \
    _Pragma("unroll")                                                       \
    for (int t = 0; t < 4; ++t)                                             \
      R[t] = *(const f16x8*)(sb_ + t * 1024);                               \
  } while (0)

#define MFMA_HALF(AP, J2, B)                                                \
  do {                                                                      \
    f16x8 a0_ = *(const f16x8*)((AP) + (J2) * 4096 + aroff);                \
    f16x8 a1_ = *(const f16x8*)((AP) + (J2) * 4096 + aroff + 512);          \
    _Pragma("unroll")                                                       \
    for (int t = 0; t < 4; ++t) {                                           \
      acc[0][t] = __builtin_amdgcn_mfma_f32_32x32x16_f16(a0_, B[t], acc[0][t], 0, 0, 0); \
      acc[1][t] = __builtin_amdgcn_mfma_f32_32x32x16_f16(a1_, B[t], acc[1][t], 0, 0, 0); \
    }                                                                       \
  } while (0)

  // prologue: A(0) regs -> LDS(+xf16); b0 <- kt 0; A(1) regs in flight.
  AISSUE(0);
  MEMFENCE;
  AWRITE(0);          // compiler inserts the vmcnt wait for aB
  MEMFENCE;
  BLOAD(0, b0);
  MEMFENCE;
  AISSUE(1);
  MEMFENCE;

  // BODY(S): lgkm0+barrier (A slice S visible block-wide) -> compiler-
  // scheduled region: BLOAD(b1) | MFMA half0 (b0) | BLOAD(b0') |
  // AWRITE(S+1)+xf16 store | AISSUE(S+2) | MFMA half1 (b1).
#define BODY(S)                                                             \
  do {                                                                      \
    asm volatile("s_waitcnt lgkmcnt(0)" ::: "memory");                      \
    __builtin_amdgcn_s_barrier();                                           \
    MEMFENCE;                                                               \
    BLOAD(2 * (S) + 1, b1);                                                 \
    const unsigned char* ap_ = &ldsA[(S) & 1][0];                           \
    __builtin_amdgcn_s_setprio(1);                                          \
    MFMA_HALF(ap_, 0, b0);                                                  \
    __builtin_amdgcn_s_setprio(0);                                          \
    BLOAD(2 * (S) + 2, b0);                                                 \
    AWRITE((S) + 1);                                                        \
    AISSUE(((S) + 2) & 15);                                                 \
    __builtin_amdgcn_s_setprio(1);                                          \
    MFMA_HALF(ap_, 1, b1);                                                  \
    __builtin_amdgcn_s_setprio(0);                                          \
  } while (0)

  // fully unrolled: literal S folds all offsets to immediates
  BODY(0);  BODY(1);  BODY(2);  BODY(3);
  BODY(4);  BODY(5);  BODY(6);  BODY(7);
  BODY(8);  BODY(9);  BODY(10); BODY(11);
  BODY(12); BODY(13); BODY(14); BODY(15);

  // epilogue: tanh + query-dot; 32-lane reduce; combine cg halves
  float sp[2][16];
#pragma unroll
  for (int f = 0; f < 2; ++f)
#pragma unroll
    for (int r = 0; r < 16; ++r) sp[f][r] = 0.f;
#pragma unroll
  for (int j = 0; j < 4; ++j) {
    const int col = ny * 256 + (cg * 4 + j) * 32 + l31;
    const float bb2 = bias[col];
    const float qq = query[col];
#pragma unroll
    for (int f = 0; f < 2; ++f)
#pragma unroll
      for (int r = 0; r < 16; ++r)
        sp[f][r] += fast_tanh(acc[f][j][r] + bb2) * qq;
  }
  __syncthreads();
#pragma unroll
  for (int f = 0; f < 2; ++f)
#pragma unroll
    for (int r = 0; r < 16; ++r) {
      float v = sp[f][r];
      v += __shfl_xor(v, 1);
      v += __shfl_xor(v, 2);
      v += __shfl_xor(v, 4);
      v += __shfl_xor(v, 8);
      v += __shfl_xor(v, 16);
      if (l31 == 0)  // C row = (r&3) + 8*(r>>2) + 4*kh  (m74/m101 layout)
        comb[cg][rg * 64 + f * 32 + (r & 3) + 8 * (r >> 2) + 4 * kh] = v;
    }
  __syncthreads();
  if (tid < 128)
    score_part[(size_t)ny * N + brow0 + tid] = comb[0][tid] + comb[1][tid];
}

// Per-graph: segmented softmax over (sp0+sp1) + weighted sum of x rows.
// If xf16 is valid (useX16), the weighted pass reads the f16 copy written by
// the GEMM (half the HBM bytes of the f32 x).
__global__ __launch_bounds__(256) void k_softmax_out(
    const float* __restrict__ x, const _Float16* __restrict__ xf16,
    const void* __restrict__ segp, const float* __restrict__ sp0,
    const float* __restrict__ sp1, float* __restrict__ out,
    int N, int useX16) {
  const int g = blockIdx.x;
  const int tid = threadIdx.x;

  // dtype probe: int64 element N/2-1 is a graph id (<NG) iff buffer is int64.
  const long long probe = ((const long long*)segp)[N / 2 - 1];
  const bool is64 = ((unsigned long long)probe < (unsigned long long)NG);
  const long long* s64 = (const long long*)segp;
  const int* s32 = (const int*)segp;

  int s0, s1;
  {
    int lo = 0, hi = N;
    while (lo < hi) {
      int m = (lo + hi) >> 1;
      long long v = is64 ? s64[m] : (long long)s32[m];
      if (v < (long long)g) lo = m + 1; else hi = m;
    }
    s0 = lo;
    lo = s0; hi = N;
    while (lo < hi) {
      int m = (lo + hi) >> 1;
      long long v = is64 ? s64[m] : (long long)s32[m];
      if (v < (long long)(g + 1)) lo = m + 1; else hi = m;
    }
    s1 = lo;
  }

  __shared__ float red[4];
  __shared__ float wbuf[512];

  float lm = -INFINITY;
  for (int i = s0 + tid; i < s1; i += 256) lm = fmaxf(lm, sp0[i] + sp1[i]);
#pragma unroll
  for (int m = 1; m < 64; m <<= 1) lm = fmaxf(lm, __shfl_xor(lm, m));
  if ((tid & 63) == 0) red[tid >> 6] = lm;
  __syncthreads();
  const float mx = fmaxf(fmaxf(red[0], red[1]), fmaxf(red[2], red[3]));
  __syncthreads();

  float ls = 0.f;
  for (int i = s0 + tid; i < s1; i += 256) ls += expf(sp0[i] + sp1[i] - mx);
#pragma unroll
  for (int m = 1; m < 64; m <<= 1) ls += __shfl_xor(ls, m);
  if ((tid & 63) == 0) red[tid >> 6] = ls;
  __syncthreads();
  const float sum = red[0] + red[1] + red[2] + red[3];
  const float inv = sum > 0.f ? 1.0f / sum : 0.f;

  float a0 = 0.f, a1 = 0.f;
  const int c = tid * 2;
  for (int base = s0; base < s1; base += 512) {
    const int cnt = min(512, s1 - base);
    __syncthreads();
    for (int i = tid; i < cnt; i += 256)
      wbuf[i] = expf(sp0[base + i] + sp1[base + i] - mx) * inv;
    __syncthreads();
    if (useX16) {
#pragma unroll 8
      for (int j = 0; j < cnt; ++j) {
        const float w = wbuf[j];
        const f16v2 xv = *(const f16v2*)(xf16 + (size_t)(base + j) * DD + c);
        a0 = fmaf(w, (float)xv[0], a0);
        a1 = fmaf(w, (float)xv[1], a1);
      }
    } else {
#pragma unroll 8
      for (int j = 0; j < cnt; ++j) {
        const float w = wbuf[j];
        const float2 xv = *(const float2*)(x + (size_t)(base + j) * DD + c);
        a0 = fmaf(w, xv.x, a0);
        a1 = fmaf(w, xv.y, a1);
      }
    }
  }
  float* op = out + (size_t)g * DD + c;
  op[0] = a0;
  op[1] = a1;
}

extern "C" void kernel_launch(void* const* d_in, const int* in_sizes, int n_in,
                              void* d_out, int out_size, void* d_ws, size_t ws_size,
                              hipStream_t stream) {
  const float* x = (const float*)d_in[0];
  const void* seg = d_in[1];
  const float* W = (const float*)d_in[2];
  const float* b = (const float*)d_in[3];
  const float* q = (const float*)d_in[4];
  float* out = (float*)d_out;
  const int N = in_sizes[0] / DD;  // 131072

  unsigned char* Whl = (unsigned char*)d_ws;                 // 512 KB packed W (f16)
  float* sp0 = (float*)(Whl + 524288);                       // N partial scores (ny=0)
  float* sp1 = sp0 + N;                                      // N partial scores (ny=1)
  const size_t x16off = 524288 + (size_t)2 * N * 4;          // after Whl + scores
  _Float16* xf16 = (_Float16*)((char*)d_ws + x16off);        // N x 512 f16 (134 MB)
  const int useX16 = (ws_size >= x16off + (size_t)N * DD * 2) ? 1 : 0;

  k_convert_w<<<128, 256, 0, stream>>>(W, Whl);
  dim3 grid(2, N / 128);                                     // ny fastest -> x-row cache reuse
  k_gemm_score<<<grid, 256, 0, stream>>>(x, Whl, b, q, sp0, xf16, useX16, N);
  k_softmax_out<<<NG, 256, 0, stream>>>(x, xf16, seg, sp0, sp1, out, N, useX16);
}

// Round 24
// 158.980 us; speedup vs baseline: 1.1605x; 1.1605x over previous
//
#include <hip/hip_runtime.h>

typedef _Float16 f16x8 __attribute__((ext_vector_type(8)));
typedef _Float16 f16x4 __attribute__((ext_vector_type(4)));
typedef __fp16 fp16v2 __attribute__((ext_vector_type(2)));
typedef _Float16 f16v2 __attribute__((ext_vector_type(2)));
typedef short short8 __attribute__((ext_vector_type(8)));
typedef float f32x16 __attribute__((ext_vector_type(16)));

#define DD 512
#define NG 512

#define MEMFENCE asm volatile("" ::: "memory")

static __device__ __forceinline__ f16v2 pk16(float a, float b) {
  fp16v2 p = __builtin_amdgcn_cvt_pkrtz(a, b);
  return __builtin_bit_cast(f16v2, p);
}

// fast tanh via exp2: tanh(v) = 1 - 2/(exp2(v*2*log2e)+1)  (~1e-6 abs err)
static __device__ __forceinline__ float fast_tanh(float v) {
  float e = __builtin_amdgcn_exp2f(v * 2.8853900817779268f);
  return 1.0f - 2.0f * __builtin_amdgcn_rcpf(e + 1.0f);
}

// Whl layout (f16 RTE): [ny(2)][kt(32)][ct(8)][lane(64)=khalf*32+c31][8 f16]
// B-fragment = 1 KB contiguous at kt*8192 + ct*1024 + lane*16 -> a direct
// global_load_dwordx4 per fragment is perfectly coalesced.  Whl = 512 KB,
// read by all blocks -> L2-resident.
__global__ __launch_bounds__(256) void k_convert_w(const float* __restrict__ W,
                                                   unsigned char* __restrict__ Whl) {
  int t = blockIdx.x * 256 + threadIdx.x;   // 32768 = 512 W-rows x 64 kgroups(8)
  int r512 = t >> 6, kg = t & 63;
  int ny = r512 >> 8, col = r512 & 255;
  int ct = col >> 5, c31 = col & 31;
  int kt = kg >> 1, khalf = kg & 1;
  const float* p = W + (size_t)r512 * DD + kg * 8;
  short8 h;
#pragma unroll
  for (int j = 0; j < 8; ++j) {
    _Float16 hh = (_Float16)p[j];              // RTE
    h[j] = (short)__builtin_bit_cast(unsigned short, hh);
  }
  unsigned char* dst = Whl + (size_t)ny * 262144 + (size_t)kt * 8192 +
                       ct * 1024 + (khalf * 32 + c31) * 16;
  *(short8*)dst = h;
}

// Fused GEMM(tanh-gate)+query-dot.  R22 configuration (best measured:
// 160.5 us total).  B: straight from L2-resident Whl to VGPRs (b0/b1
// single-kt sets).  A: f16 in LDS, conflict-free [kh-plane][row][16B],
// ring-2.  Per body: 1 barrier + 1 lgkm0; intra-body compiler-scheduled
// (counted waits auto-inserted).  Wave = 64 rows x 128 cols (acc[2][4] =
// 128 AGPR); block = 4 waves = 128 rows x 256 cols (ny = col half);
// 2-kt bodies, fully unrolled.  17.4 KB LDS.
__global__ __launch_bounds__(256, 2) void k_gemm_score(
    const float* __restrict__ x, const unsigned char* __restrict__ Whl,
    const float* __restrict__ bias, const float* __restrict__ query,
    float* __restrict__ score_part, int N) {
  __shared__ unsigned char ldsA[2][8192];
  __shared__ float comb[2][128];
  const int tid = threadIdx.x;
  const int wave = tid >> 6;
  const int lane = tid & 63;
  const int l31 = lane & 31;
  const int kh = lane >> 5;          // k-half within fragment
  const int rg = wave >> 1;          // row-group: rows rg*64..rg*64+63
  const int cg = wave & 1;           // col-group: cts cg*4..cg*4+3
  const int ny = blockIdx.x;
  const int brow0 = blockIdx.y * 128;

  // B direct-load base: fragment (kt, ct=cg*4+t) at + kt*8192 + t*1024
  const unsigned char* bsrc = Whl + (size_t)ny * 262144 + cg * 4096 +
                              (size_t)lane * 16;

  // A: thread covers chunks (row = tid>>2 and +64, kq = tid&3) of each
  // 128-row x 16-k slice.
  const float* asrc = x + (size_t)(brow0 + (tid >> 2)) * DD + (tid & 3) * 4;
  // f16 write: [kt-in-pair(4KB)][kh(2KB)][row(128)x16B], half = kq&1:
  const int awoff = ((tid & 3) >> 1) * 2048 + (tid >> 2) * 16 + (tid & 1) * 8;
  // f16 read: fragment row rg*64 + f*32 + l31, plane kh
  const int aroff = kh * 2048 + (rg * 64 + l31) * 16;

  f32x16 acc[2][4];
#pragma unroll
  for (int f = 0; f < 2; ++f)
#pragma unroll
    for (int j = 0; j < 4; ++j)
#pragma unroll
      for (int r = 0; r < 16; ++r) acc[f][j][r] = 0.f;

  float4 aB[4];        // A reg staging [kt-in-pair][chunk c]
  f16x8 b0[4], b1[4];  // B fragment sets (single kt each)

#define AISSUE(S)                                                           \
  do {                                                                      \
    _Pragma("unroll")                                                       \
    for (int j = 0; j < 2; ++j)                                             \
      _Pragma("unroll")                                                     \
      for (int c = 0; c < 2; ++c)                                           \
        aB[j * 2 + c] = *(const float4*)(asrc + (size_t)c * 64 * DD +       \
                                         ((2 * (S) + j) & 31) * 16);        \
  } while (0)

#define AWRITE(S)                                                           \
  do {                                                                      \
    unsigned char* base_ = &ldsA[(S) & 1][0];                               \
    _Pragma("unroll")                                                       \
    for (int j = 0; j < 2; ++j)                                             \
      _Pragma("unroll")                                                     \
      for (int c = 0; c < 2; ++c) {                                         \
        const float4 v_ = aB[j * 2 + c];                                    \
        f16v2 lo_ = pk16(v_.x, v_.y);                                       \
        f16v2 hi_ = pk16(v_.z, v_.w);                                       \
        f16x4 w_ = {lo_[0], lo_[1], hi_[0], hi_[1]};                        \
        *(f16x4*)(base_ + j * 4096 + awoff + c * 1024) = w_;                \
      }                                                                     \
  } while (0)

#define BLOAD(KT, R)                                                        \
  do {                                                                      \
    const unsigned char* sb_ = bsrc + (size_t)((KT) & 31) * 8192;           \
    _Pragma("unroll")                                                       \
    for (int t = 0; t < 4; ++t)                                             \
      R[t] = *(const f16x8*)(sb_ + t * 1024);                               \
  } while (0)

#define MFMA_HALF(AP, J2, B)                                                \
  do {                                                                      \
    f16x8 a0_ = *(const f16x8*)((AP) + (J2) * 4096 + aroff);                \
    f16x8 a1_ = *(const f16x8*)((AP) + (J2) * 4096 + aroff + 512);          \
    _Pragma("unroll")                                                       \
    for (int t = 0; t < 4; ++t) {                                           \
      acc[0][t] = __builtin_amdgcn_mfma_f32_32x32x16_f16(a0_, B[t], acc[0][t], 0, 0, 0); \
      acc[1][t] = __builtin_amdgcn_mfma_f32_32x32x16_f16(a1_, B[t], acc[1][t], 0, 0, 0); \
    }                                                                       \
  } while (0)

  // prologue: A(0) regs -> LDS; b0 <- kt 0; A(1) regs in flight.
  AISSUE(0);
  MEMFENCE;
  AWRITE(0);          // compiler inserts the vmcnt wait for aB
  MEMFENCE;
  BLOAD(0, b0);
  MEMFENCE;
  AISSUE(1);
  MEMFENCE;

  // BODY(S): lgkm0+barrier (A slice S visible block-wide) -> then a single
  // compiler-scheduled region: BLOAD(b1) | MFMA half0 (b0) | BLOAD(b0') |
  // AWRITE(S+1) | AISSUE(S+2) | MFMA half1 (b1).  Slot audit: AWRITE targets
  // slot (S+1)&1, MFMA reads slot S&1 - disjoint, intra-body reorder safe.
#define BODY(S)                                                             \
  do {                                                                      \
    asm volatile("s_waitcnt lgkmcnt(0)" ::: "memory");                      \
    __builtin_amdgcn_s_barrier();                                           \
    MEMFENCE;                                                               \
    BLOAD(2 * (S) + 1, b1);                                                 \
    const unsigned char* ap_ = &ldsA[(S) & 1][0];                           \
    __builtin_amdgcn_s_setprio(1);                                          \
    MFMA_HALF(ap_, 0, b0);                                                  \
    __builtin_amdgcn_s_setprio(0);                                          \
    BLOAD(2 * (S) + 2, b0);                                                 \
    AWRITE((S) + 1);                                                        \
    AISSUE(((S) + 2) & 15);                                                 \
    __builtin_amdgcn_s_setprio(1);                                          \
    MFMA_HALF(ap_, 1, b1);                                                  \
    __builtin_amdgcn_s_setprio(0);                                          \
  } while (0)

  // fully unrolled: literal S folds all offsets to immediates
  BODY(0);  BODY(1);  BODY(2);  BODY(3);
  BODY(4);  BODY(5);  BODY(6);  BODY(7);
  BODY(8);  BODY(9);  BODY(10); BODY(11);
  BODY(12); BODY(13); BODY(14); BODY(15);

  // epilogue: tanh + query-dot; 32-lane reduce; combine cg halves
  float sp[2][16];
#pragma unroll
  for (int f = 0; f < 2; ++f)
#pragma unroll
    for (int r = 0; r < 16; ++r) sp[f][r] = 0.f;
#pragma unroll
  for (int j = 0; j < 4; ++j) {
    const int col = ny * 256 + (cg * 4 + j) * 32 + l31;
    const float bb2 = bias[col];
    const float qq = query[col];
#pragma unroll
    for (int f = 0; f < 2; ++f)
#pragma unroll
      for (int r = 0; r < 16; ++r)
        sp[f][r] += fast_tanh(acc[f][j][r] + bb2) * qq;
  }
  __syncthreads();
#pragma unroll
  for (int f = 0; f < 2; ++f)
#pragma unroll
    for (int r = 0; r < 16; ++r) {
      float v = sp[f][r];
      v += __shfl_xor(v, 1);
      v += __shfl_xor(v, 2);
      v += __shfl_xor(v, 4);
      v += __shfl_xor(v, 8);
      v += __shfl_xor(v, 16);
      if (l31 == 0)  // C row = (r&3) + 8*(r>>2) + 4*kh  (m74/m101 layout)
        comb[cg][rg * 64 + f * 32 + (r & 3) + 8 * (r >> 2) + 4 * kh] = v;
    }
  __syncthreads();
  if (tid < 128)
    score_part[(size_t)ny * N + brow0 + tid] = comb[0][tid] + comb[1][tid];
}

// Per-graph: segmented softmax over (sp0+sp1) + weighted sum of x rows -> out[g][512]
__global__ __launch_bounds__(256) void k_softmax_out(
    const float* __restrict__ x, const void* __restrict__ segp,
    const float* __restrict__ sp0, const float* __restrict__ sp1,
    float* __restrict__ out, int N) {
  const int g = blockIdx.x;
  const int tid = threadIdx.x;

  // dtype probe: int64 element N/2-1 is a graph id (<NG) iff buffer is int64.
  const long long probe = ((const long long*)segp)[N / 2 - 1];
  const bool is64 = ((unsigned long long)probe < (unsigned long long)NG);
  const long long* s64 = (const long long*)segp;
  const int* s32 = (const int*)segp;

  int s0, s1;
  {
    int lo = 0, hi = N;
    while (lo < hi) {
      int m = (lo + hi) >> 1;
      long long v = is64 ? s64[m] : (long long)s32[m];
      if (v < (long long)g) lo = m + 1; else hi = m;
    }
    s0 = lo;
    lo = s0; hi = N;
    while (lo < hi) {
      int m = (lo + hi) >> 1;
      long long v = is64 ? s64[m] : (long long)s32[m];
      if (v < (long long)(g + 1)) lo = m + 1; else hi = m;
    }
    s1 = lo;
  }

  __shared__ float red[4];
  __shared__ float wbuf[512];

  float lm = -INFINITY;
  for (int i = s0 + tid; i < s1; i += 256) lm = fmaxf(lm, sp0[i] + sp1[i]);
#pragma unroll
  for (int m = 1; m < 64; m <<= 1) lm = fmaxf(lm, __shfl_xor(lm, m));
  if ((tid & 63) == 0) red[tid >> 6] = lm;
  __syncthreads();
  const float mx = fmaxf(fmaxf(red[0], red[1]), fmaxf(red[2], red[3]));
  __syncthreads();

  float ls = 0.f;
  for (int i = s0 + tid; i < s1; i += 256) ls += expf(sp0[i] + sp1[i] - mx);
#pragma unroll
  for (int m = 1; m < 64; m <<= 1) ls += __shfl_xor(ls, m);
  if ((tid & 63) == 0) red[tid >> 6] = ls;
  __syncthreads();
  const float sum = red[0] + red[1] + red[2] + red[3];
  const float inv = sum > 0.f ? 1.0f / sum : 0.f;

  float a0 = 0.f, a1 = 0.f;
  const int c = tid * 2;
  for (int base = s0; base < s1; base += 512) {
    const int cnt = min(512, s1 - base);
    __syncthreads();
    for (int i = tid; i < cnt; i += 256)
      wbuf[i] = expf(sp0[base + i] + sp1[base + i] - mx) * inv;
    __syncthreads();
#pragma unroll 8
    for (int j = 0; j < cnt; ++j) {
      const float w = wbuf[j];
      const float2 xv = *(const float2*)(x + (size_t)(base + j) * DD + c);
      a0 = fmaf(w, xv.x, a0);
      a1 = fmaf(w, xv.y, a1);
    }
  }
  float* op = out + (size_t)g * DD + c;
  op[0] = a0;
  op[1] = a1;
}

extern "C" void kernel_launch(void* const* d_in, const int* in_sizes, int n_in,
                              void* d_out, int out_size, void* d_ws, size_t ws_size,
                              hipStream_t stream) {
  const float* x = (const float*)d_in[0];
  const void* seg = d_in[1];
  const float* W = (const float*)d_in[2];
  const float* b = (const float*)d_in[3];
  const float* q = (const float*)d_in[4];
  float* out = (float*)d_out;
  const int N = in_sizes[0] / DD;  // 131072

  unsigned char* Whl = (unsigned char*)d_ws;                 // 512 KB packed W (f16)
  float* sp0 = (float*)(Whl + 524288);                       // N partial scores (ny=0)
  float* sp1 = sp0 + N;                                      // N partial scores (ny=1)

  k_convert_w<<<128, 256, 0, stream>>>(W, Whl);
  dim3 grid(2, N / 128);                                     // ny fastest -> x-row cache reuse
  k_gemm_score<<<grid, 256, 0, stream>>>(x, Whl, b, q, sp0, N);
  k_softmax_out<<<NG, 256, 0, stream>>>(x, seg, sp0, sp1, out, N);
}